// Round 1
// baseline (74.744 us; speedup 1.0000x reference)
//
#include <hip/hip_runtime.h>
#include <math.h>

// OFDM: per-row 64-pt complex DFT (radix-2 DIF, lane-per-bin), pilot channel
// estimate + linear interp, complex equalization.
// x: (N, 2, 64) f32 -> out: (N, 2, 64) f32.

__global__ __launch_bounds__(256) void ofdm_kernel(const float* __restrict__ x,
                                                   float* __restrict__ out,
                                                   int nrows) {
    const int lane = threadIdx.x & 63;
    const int wid  = threadIdx.x >> 6;
    const int wavesPerBlock = blockDim.x >> 6;
    const int gw = blockIdx.x * wavesPerBlock + wid;
    const int gstride = gridDim.x * wavesPerBlock;

    // ---- per-lane constants (hoisted out of row loop) ----
    // Twiddles for 6 DIF stages: stage s has half = 32>>s; upper lanes multiply
    // (partner - mine) by W_64^t, t = (lane & (half-1)) << s.
    float twc[6], tws[6], sgn[6];
    #pragma unroll
    for (int s = 0; s < 6; ++s) {
        const int half = 32 >> s;
        const bool up = (lane & half) != 0;
        const int t = (lane & (half - 1)) << s;
        const float th = (float)t * 0.0981747704246810387f; // pi/32
        twc[s] = up ? cosf(th) : 1.0f;
        tws[s] = up ? -sinf(th) : 0.0f;   // W = e^{-i th} = (cos, -sin)
        sgn[s] = up ? -1.0f : 1.0f;
    }
    // bit-reversal (6-bit) for output reordering: natural[k] = scrambled[brev(k)]
    const int brev = (int)(__brev((unsigned)lane) >> 26);
    // interpolation segment: pilots at 11,25,39,53 (spacing 14), clamped ends
    const int k = lane;
    const int seg = (k <= 25) ? 0 : (k <= 39) ? 1 : 2;
    float alpha = (float)(k - (11 + seg * 14)) * (1.0f / 14.0f);
    alpha = fminf(fmaxf(alpha, 0.0f), 1.0f);

    for (int r = gw; r < nrows; r += gstride) {
        const float* px = x + (size_t)r * 128;
        float xr = px[lane];        // real part, bin n = lane
        float xi = px[64 + lane];   // imag part

        // ---- 6-stage radix-2 DIF FFT (natural in, bit-reversed out) ----
        #pragma unroll
        for (int s = 0; s < 6; ++s) {
            const int half = 32 >> s;
            const float pr = __shfl_xor(xr, half);
            const float pi_ = __shfl_xor(xi, half);
            // lower: mine + partner ; upper: (partner - mine) * W
            const float ar = fmaf(sgn[s], xr, pr);
            const float ai = fmaf(sgn[s], xi, pi_);
            xr = ar * twc[s] - ai * tws[s];
            xi = ar * tws[s] + ai * twc[s];
        }
        // reorder to natural bin order: lane k holds F[k]
        const float fr = __shfl(xr, brev);
        const float fi = __shfl(xi, brev);

        // ---- pilot extraction (broadcasts) ----
        const float h0r = __shfl(fr, 11), h0i = __shfl(fi, 11);
        const float h1r = __shfl(fr, 25), h1i = __shfl(fi, 25);
        const float h2r = __shfl(fr, 39), h2i = __shfl(fi, 39);
        const float h3r = __shfl(fr, 53), h3i = __shfl(fi, 53);

        // ---- piecewise-linear channel interp ----
        const float har = (seg == 0) ? h0r : (seg == 1) ? h1r : h2r;
        const float hai = (seg == 0) ? h0i : (seg == 1) ? h1i : h2i;
        const float hbr = (seg == 0) ? h1r : (seg == 1) ? h2r : h3r;
        const float hbi = (seg == 0) ? h1i : (seg == 1) ? h2i : h3i;
        const float hr = fmaf(alpha, hbr - har, har);
        const float hi = fmaf(alpha, hbi - hai, hai);

        // ---- equalize ----
        const float denom = fmaf(hr, hr, fmaf(hi, hi, 1e-8f));
        const float rd = 1.0f / denom;
        const float eqr = (fr * hr + fi * hi) * rd;
        const float eqi = (fi * hr - fr * hi) * rd;

        float* po = out + (size_t)r * 128;
        po[lane] = eqr;
        po[64 + lane] = eqi;
    }
}

extern "C" void kernel_launch(void* const* d_in, const int* in_sizes, int n_in,
                              void* d_out, int out_size, void* d_ws, size_t ws_size,
                              hipStream_t stream) {
    const float* x = (const float*)d_in[0];
    float* out = (float*)d_out;
    const int nrows = in_sizes[0] / 128;   // 262144
    const int block = 256;                 // 4 waves/block
    const int grid = 2048;                 // 8192 waves, 32 rows/wave
    hipLaunchKernelGGL(ofdm_kernel, dim3(grid), dim3(block), 0, stream,
                       x, out, nrows);
}

// Round 2
// 65.968 us; speedup vs baseline: 1.1330x; 1.1330x over previous
//
#include <hip/hip_runtime.h>
#include <math.h>

// OFDM: per-row 64-pt complex FFT (radix-2 DIF, lane-per-bin), pilot channel
// estimate + linear interp, complex equalization — all in the bit-reversed
// domain (pilots at fixed scrambled lanes; scatter-store within the 256B row
// segment restores natural order at zero shuffle cost).
// x: (N, 2, 64) f32 -> out: (N, 2, 64) f32.

struct LaneConst {
    float twc[6], tws[6], sgn[6]; // DIF twiddles per stage
    float alpha;                  // interp weight for this lane's natural bin
    int   seg;                    // interp segment 0..2
    int   kk;                     // natural bin index = brev6(lane)
};

template <int R>
__device__ __forceinline__ void do_rows(const float* __restrict__ x,
                                        float* __restrict__ out,
                                        int r0, int lane, const LaneConst& c) {
    float xr[R], xi[R];
    // ---- loads: 2R independent coalesced 256B reads, all issued up front ----
    #pragma unroll
    for (int j = 0; j < R; ++j) {
        const float* px = x + (size_t)(r0 + j) * 128;
        xr[j] = __builtin_nontemporal_load(px + lane);
        xi[j] = __builtin_nontemporal_load(px + 64 + lane);
    }
    // ---- 6-stage radix-2 DIF FFT, R interleaved independent chains ----
    #pragma unroll
    for (int s = 0; s < 6; ++s) {
        const int half = 32 >> s;
        #pragma unroll
        for (int j = 0; j < R; ++j) {
            const float pr  = __shfl_xor(xr[j], half);
            const float pi_ = __shfl_xor(xi[j], half);
            const float ar = fmaf(c.sgn[s], xr[j], pr);
            const float ai = fmaf(c.sgn[s], xi[j], pi_);
            xr[j] = fmaf(ar, c.twc[s], -(ai * c.tws[s]));
            xi[j] = fmaf(ar, c.tws[s],   ai * c.twc[s]);
        }
    }
    // ---- epilogue per row, in scrambled domain ----
    // F[11]@lane52, F[25]@lane38, F[39]@lane57, F[53]@lane43 (brev6 of 11/25/39/53)
    #pragma unroll
    for (int j = 0; j < R; ++j) {
        const float h0r = __shfl(xr[j], 52), h0i = __shfl(xi[j], 52);
        const float h1r = __shfl(xr[j], 38), h1i = __shfl(xi[j], 38);
        const float h2r = __shfl(xr[j], 57), h2i = __shfl(xi[j], 57);
        const float h3r = __shfl(xr[j], 43), h3i = __shfl(xi[j], 43);
        const float har = (c.seg == 0) ? h0r : (c.seg == 1) ? h1r : h2r;
        const float hai = (c.seg == 0) ? h0i : (c.seg == 1) ? h1i : h2i;
        const float hbr = (c.seg == 0) ? h1r : (c.seg == 1) ? h2r : h3r;
        const float hbi = (c.seg == 0) ? h1i : (c.seg == 1) ? h2i : h3i;
        const float hr = fmaf(c.alpha, hbr - har, har);
        const float hi = fmaf(c.alpha, hbi - hai, hai);
        const float denom = fmaf(hr, hr, fmaf(hi, hi, 1e-8f));
        const float rd = __builtin_amdgcn_rcpf(denom);
        const float eqr = fmaf(xr[j], hr,  xi[j] * hi) * rd;
        const float eqi = fmaf(xi[j], hr, -(xr[j] * hi)) * rd;
        float* po = out + (size_t)(r0 + j) * 128;
        __builtin_nontemporal_store(eqr, po + c.kk);
        __builtin_nontemporal_store(eqi, po + 64 + c.kk);
    }
}

__global__ __launch_bounds__(256) void ofdm_kernel(const float* __restrict__ x,
                                                   float* __restrict__ out,
                                                   int nrows) {
    const int lane = threadIdx.x & 63;
    const int wid  = threadIdx.x >> 6;
    const int wavesPerBlock = blockDim.x >> 6;
    const int gw = blockIdx.x * wavesPerBlock + wid;
    const int gstride = gridDim.x * wavesPerBlock;

    LaneConst c;
    #pragma unroll
    for (int s = 0; s < 6; ++s) {
        const int half = 32 >> s;
        const bool up = (lane & half) != 0;
        const int t = (lane & (half - 1)) << s;
        const float th = (float)t * 0.0981747704246810387f; // pi/32
        c.twc[s] = up ? cosf(th) : 1.0f;
        c.tws[s] = up ? -sinf(th) : 0.0f;   // W = e^{-i th}
        c.sgn[s] = up ? -1.0f : 1.0f;
    }
    c.kk = (int)(__brev((unsigned)lane) >> 26);        // natural bin this lane holds
    c.seg = (c.kk <= 25) ? 0 : (c.kk <= 39) ? 1 : 2;   // pilots 11,25,39,53 (Δ=14)
    float a = (float)(c.kk - (11 + c.seg * 14)) * (1.0f / 14.0f);
    c.alpha = fminf(fmaxf(a, 0.0f), 1.0f);

    constexpr int R = 4;
    const int step = gstride * R;
    int r = gw * R;
    for (; r + R <= nrows; r += step)
        do_rows<R>(x, out, r, lane, c);
    if (r < nrows)                        // tail (unused for nrows % 4 == 0)
        for (; r < nrows; ++r)
            do_rows<1>(x, out, r, lane, c);
}

extern "C" void kernel_launch(void* const* d_in, const int* in_sizes, int n_in,
                              void* d_out, int out_size, void* d_ws, size_t ws_size,
                              hipStream_t stream) {
    const float* x = (const float*)d_in[0];
    float* out = (float*)d_out;
    const int nrows = in_sizes[0] / 128;   // 262144
    const int block = 256;                 // 4 waves/block
    const int grid = 2048;                 // 8192 waves, 8 iters x 4 rows each
    hipLaunchKernelGGL(ofdm_kernel, dim3(grid), dim3(block), 0, stream,
                       x, out, nrows);
}

// Round 3
// 47.889 us; speedup vs baseline: 1.5608x; 1.3775x over previous
//
#include <hip/hip_runtime.h>
#include <math.h>

// OFDM: per-row 64-pt complex FFT (radix-2 DIF, lane-per-bin) with
// VALU-only cross-lane stages where gfx950 allows:
//   xor32 -> v_permlane32_swap_b32, xor16 -> v_permlane16_swap_b32,
//   xor8/xor4 -> ds_swizzle, xor2/xor1 -> DPP quad_perm.
// Epilogue (pilot estimate + interp + equalize) in bit-reversed domain;
// scatter-store within the 256B row segment restores natural order.

typedef unsigned int uint2v __attribute__((ext_vector_type(2)));

struct LaneConst {
    float twc[6], tws[6], sgn[6]; // DIF twiddles / butterfly signs per stage
    float w0, w1, w2, w3;         // pilot interpolation weights for this lane
    int   kk;                     // natural bin index = brev6(lane)
};

template <int CTRL>
__device__ __forceinline__ float dpp_mov(float x) {
    return __int_as_float(__builtin_amdgcn_update_dpp(
        0, __float_as_int(x), CTRL, 0xF, 0xF, true));
}

__device__ __forceinline__ float rdlane(float x, int l) {
    return __int_as_float(__builtin_amdgcn_readlane(__float_as_int(x), l));
}

template <int R>
__device__ __forceinline__ void do_rows(const float* __restrict__ x,
                                        float* __restrict__ out,
                                        int r0, int lane, const LaneConst& c) {
    float xr[R], xi[R];
    #pragma unroll
    for (int j = 0; j < R; ++j) {
        const float* px = x + (size_t)(r0 + j) * 128;
        xr[j] = px[lane];
        xi[j] = px[64 + lane];
    }

    #pragma unroll
    for (int j = 0; j < R; ++j) {
        float ar, ai, t;
        // ---- stage 0: xor32 via permlane32_swap (VALU) ----
#if __has_builtin(__builtin_amdgcn_permlane32_swap)
        {
            uint2v tr = __builtin_amdgcn_permlane32_swap(
                (unsigned)__float_as_int(xr[j]), (unsigned)__float_as_int(xr[j]), false, false);
            uint2v ti = __builtin_amdgcn_permlane32_swap(
                (unsigned)__float_as_int(xi[j]), (unsigned)__float_as_int(xi[j]), false, false);
            // tr[0] = low-half dup, tr[1] = high-half dup
            ar = fmaf(c.sgn[0], __int_as_float((int)tr[1]), __int_as_float((int)tr[0]));
            ai = fmaf(c.sgn[0], __int_as_float((int)ti[1]), __int_as_float((int)ti[0]));
        }
#else
        ar = fmaf(c.sgn[0], xr[j], __shfl_xor(xr[j], 32));
        ai = fmaf(c.sgn[0], xi[j], __shfl_xor(xi[j], 32));
#endif
        t = fmaf(ar, c.twc[0], -(ai * c.tws[0]));
        xi[j] = fmaf(ar, c.tws[0], ai * c.twc[0]);
        xr[j] = t;

        // ---- stage 1: xor16 via permlane16_swap (VALU) ----
#if __has_builtin(__builtin_amdgcn_permlane16_swap)
        {
            uint2v tr = __builtin_amdgcn_permlane16_swap(
                (unsigned)__float_as_int(xr[j]), (unsigned)__float_as_int(xr[j]), false, false);
            uint2v ti = __builtin_amdgcn_permlane16_swap(
                (unsigned)__float_as_int(xi[j]), (unsigned)__float_as_int(xi[j]), false, false);
            ar = fmaf(c.sgn[1], __int_as_float((int)tr[1]), __int_as_float((int)tr[0]));
            ai = fmaf(c.sgn[1], __int_as_float((int)ti[1]), __int_as_float((int)ti[0]));
        }
#else
        ar = fmaf(c.sgn[1], xr[j], __shfl_xor(xr[j], 16));
        ai = fmaf(c.sgn[1], xi[j], __shfl_xor(xi[j], 16));
#endif
        t = fmaf(ar, c.twc[1], -(ai * c.tws[1]));
        xi[j] = fmaf(ar, c.tws[1], ai * c.twc[1]);
        xr[j] = t;

        // ---- stage 2: xor8 via ds_swizzle ----
        {
            float pr = __int_as_float(__builtin_amdgcn_ds_swizzle(__float_as_int(xr[j]), 0x201F));
            float pi_ = __int_as_float(__builtin_amdgcn_ds_swizzle(__float_as_int(xi[j]), 0x201F));
            ar = fmaf(c.sgn[2], xr[j], pr);
            ai = fmaf(c.sgn[2], xi[j], pi_);
        }
        t = fmaf(ar, c.twc[2], -(ai * c.tws[2]));
        xi[j] = fmaf(ar, c.tws[2], ai * c.twc[2]);
        xr[j] = t;

        // ---- stage 3: xor4 via ds_swizzle ----
        {
            float pr = __int_as_float(__builtin_amdgcn_ds_swizzle(__float_as_int(xr[j]), 0x101F));
            float pi_ = __int_as_float(__builtin_amdgcn_ds_swizzle(__float_as_int(xi[j]), 0x101F));
            ar = fmaf(c.sgn[3], xr[j], pr);
            ai = fmaf(c.sgn[3], xi[j], pi_);
        }
        t = fmaf(ar, c.twc[3], -(ai * c.tws[3]));
        xi[j] = fmaf(ar, c.tws[3], ai * c.twc[3]);
        xr[j] = t;

        // ---- stage 4: xor2 via DPP quad_perm [2,3,0,1] = 0x4E ----
        ar = fmaf(c.sgn[4], xr[j], dpp_mov<0x4E>(xr[j]));
        ai = fmaf(c.sgn[4], xi[j], dpp_mov<0x4E>(xi[j]));
        t = fmaf(ar, c.twc[4], -(ai * c.tws[4]));
        xi[j] = fmaf(ar, c.tws[4], ai * c.twc[4]);
        xr[j] = t;

        // ---- stage 5: xor1 via DPP quad_perm [1,0,3,2] = 0xB1 ----
        ar = fmaf(c.sgn[5], xr[j], dpp_mov<0xB1>(xr[j]));
        ai = fmaf(c.sgn[5], xi[j], dpp_mov<0xB1>(xi[j]));
        t = fmaf(ar, c.twc[5], -(ai * c.tws[5]));
        xi[j] = fmaf(ar, c.tws[5], ai * c.twc[5]);
        xr[j] = t;
    }

    // ---- epilogue per row, scrambled domain ----
    // F[11]@lane52, F[25]@lane38, F[39]@lane57, F[53]@lane43 (brev6)
    #pragma unroll
    for (int j = 0; j < R; ++j) {
        const float h0r = rdlane(xr[j], 52), h0i = rdlane(xi[j], 52);
        const float h1r = rdlane(xr[j], 38), h1i = rdlane(xi[j], 38);
        const float h2r = rdlane(xr[j], 57), h2i = rdlane(xi[j], 57);
        const float h3r = rdlane(xr[j], 43), h3i = rdlane(xi[j], 43);
        float hr = c.w0 * h0r;
        hr = fmaf(c.w1, h1r, hr);
        hr = fmaf(c.w2, h2r, hr);
        hr = fmaf(c.w3, h3r, hr);
        float hi = c.w0 * h0i;
        hi = fmaf(c.w1, h1i, hi);
        hi = fmaf(c.w2, h2i, hi);
        hi = fmaf(c.w3, h3i, hi);
        const float denom = fmaf(hr, hr, fmaf(hi, hi, 1e-8f));
        const float rd = __builtin_amdgcn_rcpf(denom);
        const float eqr = fmaf(xr[j], hr,  xi[j] * hi) * rd;
        const float eqi = fmaf(xi[j], hr, -(xr[j] * hi)) * rd;
        float* po = out + (size_t)(r0 + j) * 128;
        __builtin_nontemporal_store(eqr, po + c.kk);
        __builtin_nontemporal_store(eqi, po + 64 + c.kk);
    }
}

__global__ __launch_bounds__(256) void ofdm_kernel(const float* __restrict__ x,
                                                   float* __restrict__ out,
                                                   int nrows) {
    const int lane = threadIdx.x & 63;
    const int wid  = threadIdx.x >> 6;
    const int wavesPerBlock = blockDim.x >> 6;
    const int gw = blockIdx.x * wavesPerBlock + wid;
    const int gstride = gridDim.x * wavesPerBlock;

    LaneConst c;
    #pragma unroll
    for (int s = 0; s < 6; ++s) {
        const int half = 32 >> s;
        const bool up = (lane & half) != 0;
        const int t = (lane & (half - 1)) << s;
        const float th = (float)t * 0.0981747704246810387f; // pi/32
        c.twc[s] = up ? cosf(th) : 1.0f;
        c.tws[s] = up ? -sinf(th) : 0.0f;   // W = e^{-i th}
        c.sgn[s] = up ? -1.0f : 1.0f;
    }
    c.kk = (int)(__brev((unsigned)lane) >> 26);
    // pilot interp weights: pilots at 11,25,39,53 (spacing 14), clamped ends
    const int seg = (c.kk <= 25) ? 0 : (c.kk <= 39) ? 1 : 2;
    float a = (float)(c.kk - (11 + seg * 14)) * (1.0f / 14.0f);
    a = fminf(fmaxf(a, 0.0f), 1.0f);
    c.w0 = c.w1 = c.w2 = c.w3 = 0.0f;
    float wa = 1.0f - a, wb = a;
    if (seg == 0) { c.w0 = wa; c.w1 = wb; }
    else if (seg == 1) { c.w1 = wa; c.w2 = wb; }
    else { c.w2 = wa; c.w3 = wb; }

    constexpr int R = 8;
    const int step = gstride * R;
    int r = gw * R;
    for (; r + R <= nrows; r += step)
        do_rows<R>(x, out, r, lane, c);
    for (; r < nrows; ++r)
        do_rows<1>(x, out, r, lane, c);
}

extern "C" void kernel_launch(void* const* d_in, const int* in_sizes, int n_in,
                              void* d_out, int out_size, void* d_ws, size_t ws_size,
                              hipStream_t stream) {
    const float* x = (const float*)d_in[0];
    float* out = (float*)d_out;
    const int nrows = in_sizes[0] / 128;   // 262144
    const int block = 256;                 // 4 waves/block
    const int grid = 2048;                 // 8192 waves, 4 iters x 8 rows
    hipLaunchKernelGGL(ofdm_kernel, dim3(grid), dim3(block), 0, stream,
                       x, out, nrows);
}